// Round 1
// baseline (289.569 us; speedup 1.0000x reference)
//
#include <hip/hip_runtime.h>

// Problem constants (from reference setup_inputs).
constexpr int B = 8, C = 16, H = 256, W = 256;
constexpr float INV2S2 = 8.0f;          // 1 / (2 * 0.25^2)
constexpr int HW = H * W;

// One thread per output pixel (b, ho, wo); handles all C=16 channels.
// x = wo - w0*(W-1)/2, y = ho - w1*(H-1)/2  (identity grid cancels).
// Separable Gaussian weights, validity folded into the weight.
__global__ __launch_bounds__(256) void gauss_warp_kernel(
    const float* __restrict__ im, const float* __restrict__ w,
    float* __restrict__ out) {
  const int idx = blockIdx.x * 256 + threadIdx.x;   // grid sized exactly
  const int wo = idx & (W - 1);
  const int ho = (idx >> 8) & (H - 1);
  const int b  = idx >> 16;

  const int pix = ho * W + wo;
  const float w0 = w[(size_t)(b * 2 + 0) * HW + pix];
  const float w1 = w[(size_t)(b * 2 + 1) * HW + pix];

  const float x = (float)wo - w0 * (0.5f * (float)(W - 1));
  const float y = (float)ho - w1 * (0.5f * (float)(H - 1));
  const int ix = (int)floorf(x);
  const int iy = (int)floorf(y);

  float wx[3], wy[3];
  int xc[3], yc[3];
#pragma unroll
  for (int d = 0; d < 3; ++d) {
    const int xi = ix + d - 1;
    const float dx = x - (float)xi;
    wx[d] = (xi >= 0 && xi < W) ? __expf(-dx * dx * INV2S2) : 0.0f;
    xc[d] = min(max(xi, 0), W - 1);
    const int yi = iy + d - 1;
    const float dy = y - (float)yi;
    wy[d] = (yi >= 0 && yi < H) ? __expf(-dy * dy * INV2S2) : 0.0f;
    yc[d] = min(max(yi, 0), H - 1);
  }

  // Precombined 3x3 weights and flat offsets (shared across channels).
  float wgt[9];
  int off[9];
#pragma unroll
  for (int dy = 0; dy < 3; ++dy) {
#pragma unroll
    for (int dx = 0; dx < 3; ++dx) {
      wgt[dy * 3 + dx] = wy[dy] * wx[dx];
      off[dy * 3 + dx] = yc[dy] * W + xc[dx];
    }
  }

  const float* __restrict__ imb = im + (size_t)b * C * HW;
  float* __restrict__ ob = out + (size_t)b * C * HW + pix;

#pragma unroll 4
  for (int c = 0; c < C; ++c) {
    const float* __restrict__ p = imb + (size_t)c * HW;
    float acc = 0.0f;
#pragma unroll
    for (int t = 0; t < 9; ++t) acc = fmaf(wgt[t], p[off[t]], acc);
    ob[(size_t)c * HW] = acc;
  }
}

extern "C" void kernel_launch(void* const* d_in, const int* in_sizes, int n_in,
                              void* d_out, int out_size, void* d_ws, size_t ws_size,
                              hipStream_t stream) {
  const float* im = (const float*)d_in[0];
  const float* w  = (const float*)d_in[1];
  float* out = (float*)d_out;

  const int total = B * H * W;           // 524288 threads, one per pixel
  dim3 grid(total / 256), block(256);
  gauss_warp_kernel<<<grid, block, 0, stream>>>(im, w, out);
}

// Round 4
// 113.912 us; speedup vs baseline: 2.5421x; 2.5421x over previous
//
#include <hip/hip_runtime.h>

// Problem constants (from reference setup_inputs).
constexpr int B = 8, C = 16, H = 256, W = 256;
constexpr float INV2S2 = 8.0f;          // 1 / (2 * 0.25^2)
constexpr int HW = H * W;

// ---------------------------------------------------------------------------
// Kernel A: transpose im (B,C,H,W) -> (B,H,W,C) into workspace.
// One thread per pixel: 16 coalesced scalar reads, 4 float4 writes.
// ---------------------------------------------------------------------------
__global__ __launch_bounds__(256) void transpose_nchw_nhwc(
    const float* __restrict__ im, float* __restrict__ nhwc) {
  const int idx = blockIdx.x * 256 + threadIdx.x;   // over B*H*W
  const int b = idx >> 16;
  const int pix = idx & (HW - 1);
  const float* __restrict__ src = im + (size_t)b * C * HW + pix;
  float v[C];
#pragma unroll
  for (int c = 0; c < C; ++c) v[c] = src[(size_t)c * HW];
  float4* __restrict__ dst = (float4*)(nhwc + (size_t)idx * C);
#pragma unroll
  for (int q = 0; q < 4; ++q)
    dst[q] = make_float4(v[4 * q], v[4 * q + 1], v[4 * q + 2], v[4 * q + 3]);
}

// ---------------------------------------------------------------------------
// Kernel B: Gaussian warp gather from NHWC.
// 4 consecutive lanes per output pixel; lane owns channel quad cq = lane&3.
// Per tap: one float4 load; the 4 lanes' addresses are one contiguous 64B
// line -> coalesces to a single L1/L2 request per tap per pixel.
// Output written directly in NCHW.
// ---------------------------------------------------------------------------
__global__ __launch_bounds__(256) void gauss_warp_nhwc(
    const float* __restrict__ nhwc, const float* __restrict__ w,
    float* __restrict__ out) {
  const int t = blockIdx.x * 256 + threadIdx.x;   // over B*H*W*4
  const int cq  = t & 3;        // channel quad (0..3)
  const int idx = t >> 2;       // pixel index over B*H*W
  const int wo = idx & (W - 1);
  const int ho = (idx >> 8) & (H - 1);
  const int b  = idx >> 16;
  const int pix = ho * W + wo;

  const float w0 = w[(size_t)(b * 2 + 0) * HW + pix];
  const float w1 = w[(size_t)(b * 2 + 1) * HW + pix];

  const float x = (float)wo - w0 * (0.5f * (float)(W - 1));
  const float y = (float)ho - w1 * (0.5f * (float)(H - 1));
  const int ix = (int)floorf(x);
  const int iy = (int)floorf(y);

  float wx[3], wy[3];
  int xc[3], yc[3];
#pragma unroll
  for (int d = 0; d < 3; ++d) {
    const int xi = ix + d - 1;
    const float dx = x - (float)xi;
    wx[d] = (xi >= 0 && xi < W) ? __expf(-dx * dx * INV2S2) : 0.0f;
    xc[d] = min(max(xi, 0), W - 1);
    const int yi = iy + d - 1;
    const float dy = y - (float)yi;
    wy[d] = (yi >= 0 && yi < H) ? __expf(-dy * dy * INV2S2) : 0.0f;
    yc[d] = min(max(yi, 0), H - 1);
  }

  const float* __restrict__ base = nhwc + ((size_t)b * HW) * C + cq * 4;
  float4 acc = make_float4(0.f, 0.f, 0.f, 0.f);
#pragma unroll
  for (int dy = 0; dy < 3; ++dy) {
#pragma unroll
    for (int dx = 0; dx < 3; ++dx) {
      const float g = wy[dy] * wx[dx];
      const int off = yc[dy] * W + xc[dx];
      const float4 v = *(const float4*)(base + (size_t)off * C);
      acc.x = fmaf(g, v.x, acc.x);
      acc.y = fmaf(g, v.y, acc.y);
      acc.z = fmaf(g, v.z, acc.z);
      acc.w = fmaf(g, v.w, acc.w);
    }
  }

  float* __restrict__ ob = out + (size_t)b * C * HW + (size_t)(cq * 4) * HW + pix;
  ob[0]          = acc.x;
  ob[(size_t)HW]     = acc.y;
  ob[(size_t)2 * HW] = acc.z;
  ob[(size_t)3 * HW] = acc.w;
}

// ---------------------------------------------------------------------------
// Fallback (round-1 kernel): direct NCHW gather, used only if ws too small.
// ---------------------------------------------------------------------------
__global__ __launch_bounds__(256) void gauss_warp_kernel(
    const float* __restrict__ im, const float* __restrict__ w,
    float* __restrict__ out) {
  const int idx = blockIdx.x * 256 + threadIdx.x;
  const int wo = idx & (W - 1);
  const int ho = (idx >> 8) & (H - 1);
  const int b  = idx >> 16;
  const int pix = ho * W + wo;
  const float w0 = w[(size_t)(b * 2 + 0) * HW + pix];
  const float w1 = w[(size_t)(b * 2 + 1) * HW + pix];
  const float x = (float)wo - w0 * (0.5f * (float)(W - 1));
  const float y = (float)ho - w1 * (0.5f * (float)(H - 1));
  const int ix = (int)floorf(x);
  const int iy = (int)floorf(y);
  float wx[3], wy[3];
  int xc[3], yc[3];
#pragma unroll
  for (int d = 0; d < 3; ++d) {
    const int xi = ix + d - 1;
    const float dx = x - (float)xi;
    wx[d] = (xi >= 0 && xi < W) ? __expf(-dx * dx * INV2S2) : 0.0f;
    xc[d] = min(max(xi, 0), W - 1);
    const int yi = iy + d - 1;
    const float dy = y - (float)yi;
    wy[d] = (yi >= 0 && yi < H) ? __expf(-dy * dy * INV2S2) : 0.0f;
    yc[d] = min(max(yi, 0), H - 1);
  }
  float wgt[9];
  int off[9];
#pragma unroll
  for (int dy = 0; dy < 3; ++dy)
#pragma unroll
    for (int dx = 0; dx < 3; ++dx) {
      wgt[dy * 3 + dx] = wy[dy] * wx[dx];
      off[dy * 3 + dx] = yc[dy] * W + xc[dx];
    }
  const float* __restrict__ imb = im + (size_t)b * C * HW;
  float* __restrict__ ob = out + (size_t)b * C * HW + pix;
#pragma unroll 4
  for (int c = 0; c < C; ++c) {
    const float* __restrict__ p = imb + (size_t)c * HW;
    float acc = 0.0f;
#pragma unroll
    for (int t = 0; t < 9; ++t) acc = fmaf(wgt[t], p[off[t]], acc);
    ob[(size_t)c * HW] = acc;
  }
}

extern "C" void kernel_launch(void* const* d_in, const int* in_sizes, int n_in,
                              void* d_out, int out_size, void* d_ws, size_t ws_size,
                              hipStream_t stream) {
  const float* im = (const float*)d_in[0];
  const float* w  = (const float*)d_in[1];
  float* out = (float*)d_out;

  const size_t need = (size_t)B * C * HW * sizeof(float);   // 32 MiB
  if (ws_size >= need) {
    float* nhwc = (float*)d_ws;
    const int px = B * H * W;                 // 524288
    transpose_nchw_nhwc<<<px / 256, 256, 0, stream>>>(im, nhwc);
    gauss_warp_nhwc<<<px * 4 / 256, 256, 0, stream>>>(nhwc, w, out);
  } else {
    const int total = B * H * W;
    gauss_warp_kernel<<<total / 256, 256, 0, stream>>>(im, w, out);
  }
}